// Round 15
// baseline (160.693 us; speedup 1.0000x reference)
//
#include <hip/hip_runtime.h>
#include <stdint.h>

#define BB 8
#define NN 100000
#define NN2 50000         // NN/2 pairs per batch
#define CC 18
#define DD 128
#define NCROSS 1024
#define TOPK 256
#define NBINS 8192
#define CCAP 4096
#define RBLK 64           // positions per k_rank2 block

// d_out float offsets (outputs concatenated flat in return order)
#define OFF_PTS 0
#define OFF_FEAT 6144
#define OFF_SI 268288
#define OFF_CROSS 270336

typedef float f32x4 __attribute__((ext_vector_type(4)));
typedef float f32x2 __attribute__((ext_vector_type(2)));

// sigmoid with correctly-rounded f32 exp — bit-matched numpy f32 pipeline
__device__ __forceinline__ float sigf(float x) {
  float e = (float)exp(-(double)x);
  return 1.0f / (1.0f + e);
}

__global__ void k_init(uint32_t* __restrict__ p, int n) {
  int i = blockIdx.x * 256 + threadIdx.x;
  if (i < n) p[i] = 0u;
}

// v4 = r12's proven v2 with ONE change: cls/cen loads are NON-TEMPORAL
// (cache-allocate bypass). Tests whether the ~0.55 TB/s cold-read ceiling is
// a cache-path artifact vs allocation-fundamental.
__global__ void k_score_v4(const float* __restrict__ cen, const float* __restrict__ cls,
                           uint32_t* __restrict__ keys, uint32_t* __restrict__ hist) {
  int b = blockIdx.y;
  int j = blockIdx.x * 256 + threadIdx.x;  // pair index within batch
  __shared__ uint32_t h[NBINS];  // 32 KB
  for (int i = threadIdx.x; i < NBINS; i += 256) h[i] = 0u;
  __syncthreads();
  if (j < NN2) {
    const f32x4* q = (const f32x4*)(cls + (size_t)b * NN * CC) + (size_t)j * 9;
    f32x4 a0 = __builtin_nontemporal_load(q + 0);
    f32x4 a1 = __builtin_nontemporal_load(q + 1);
    f32x4 a2 = __builtin_nontemporal_load(q + 2);
    f32x4 a3 = __builtin_nontemporal_load(q + 3);
    f32x4 a4 = __builtin_nontemporal_load(q + 4);
    f32x4 a5 = __builtin_nontemporal_load(q + 5);
    f32x4 a6 = __builtin_nontemporal_load(q + 6);
    f32x4 a7 = __builtin_nontemporal_load(q + 7);
    f32x4 a8 = __builtin_nontemporal_load(q + 8);
    float m0 = fmaxf(fmaxf(fmaxf(a0[0], a0[1]), fmaxf(a0[2], a0[3])),
                     fmaxf(fmaxf(a1[0], a1[1]), fmaxf(a1[2], a1[3])));
    m0 = fmaxf(m0, fmaxf(fmaxf(a2[0], a2[1]), fmaxf(a2[2], a2[3])));
    m0 = fmaxf(m0, fmaxf(fmaxf(a3[0], a3[1]), fmaxf(a3[2], a3[3])));
    m0 = fmaxf(m0, fmaxf(a4[0], a4[1]));
    float m1 = fmaxf(a4[2], a4[3]);
    m1 = fmaxf(m1, fmaxf(fmaxf(a5[0], a5[1]), fmaxf(a5[2], a5[3])));
    m1 = fmaxf(m1, fmaxf(fmaxf(a6[0], a6[1]), fmaxf(a6[2], a6[3])));
    m1 = fmaxf(m1, fmaxf(fmaxf(a7[0], a7[1]), fmaxf(a7[2], a7[3])));
    m1 = fmaxf(m1, fmaxf(fmaxf(a8[0], a8[1]), fmaxf(a8[2], a8[3])));
    f32x2 ce = __builtin_nontemporal_load((const f32x2*)(cen + (size_t)b * NN) + j);
    // max_c fl(sig_cen*sig_cls_c) == fl(sig_cen * sig(max_c cls_c)) (monotone)
    float s0 = sigf(m0) * sigf(ce[0]);
    float s1 = sigf(m1) * sigf(ce[1]);
    uint32_t k0 = __float_as_uint(s0), k1 = __float_as_uint(s1);
    ((uint2*)(keys + (size_t)b * NN))[j] = make_uint2(k0, k1);
    atomicAdd(&h[k0 >> 19], 1u);
    atomicAdd(&h[k1 >> 19], 1u);
  }
  __syncthreads();
  for (int i = threadIdx.x; i < NBINS; i += 256) {
    uint32_t v = h[i];
    if (v) atomicAdd(&hist[b * NBINS + i], v);
  }
}

// PROVEN GREEN verbatim.
__global__ void k_select(const uint32_t* __restrict__ hist, uint32_t* __restrict__ cutoff) {
  int b = blockIdx.x;
  int t = threadIdx.x;
  __shared__ uint32_t h[NBINS];     // 32 KB
  __shared__ uint32_t csum[256];
  for (int j = t; j < NBINS; j += 256) h[j] = hist[b * NBINS + j];
  __syncthreads();
  uint32_t s = 0;
  int base = t * 32;
#pragma unroll
  for (int j = 0; j < 32; ++j) s += h[base + ((j + t) & 31)];
  csum[t] = s;
  __syncthreads();
  for (int off = 1; off < 256; off <<= 1) {
    uint32_t v = csum[t];
    uint32_t a = (t + off < 256) ? csum[t + off] : 0u;
    __syncthreads();
    csum[t] = v + a;
    __syncthreads();
  }
  uint32_t St = csum[t];
  uint32_t St1 = (t < 255) ? csum[t + 1] : 0u;
  if (St >= NCROSS && St1 < NCROSS) {
    uint32_t acc = St1;
    int cb = base;
    for (int bin = base + 31; bin >= base; --bin) {
      acc += h[bin];
      if (acc >= NCROSS) { cb = bin; break; }
    }
    cutoff[b] = (uint32_t)cb;
  }
}

// PROVEN GREEN verbatim: wave-aggregated atomics.
__global__ void k_compact(const uint32_t* __restrict__ keys, const uint32_t* __restrict__ cutoff,
                          uint32_t* __restrict__ cand_cnt, uint32_t* __restrict__ cand_key,
                          uint32_t* __restrict__ cand_idx) {
  int b = blockIdx.y;
  int n = blockIdx.x * 256 + threadIdx.x;
  bool pass = false;
  uint32_t k = 0;
  if (n < NN) {
    k = keys[b * NN + n];
    pass = (k >> 19) >= cutoff[b];
  }
  int lane = threadIdx.x & 63;
  unsigned long long mask = __ballot(pass);
  if (mask) {
    int leader = __ffsll(mask) - 1;
    uint32_t wbase = 0;
    if (lane == leader) wbase = atomicAdd(&cand_cnt[b], (uint32_t)__popcll(mask));
    wbase = __shfl(wbase, leader);
    if (pass) {
      uint32_t pos = wbase + (uint32_t)__popcll(mask & ((1ull << lane) - 1ull));
      if (pos < CCAP) {
        cand_key[b * CCAP + pos] = k;
        cand_idx[b * CCAP + pos] = (uint32_t)n;
      }
    }
  }
}

// PROVEN GREEN (r9): 4-wave-per-position broadcast ranking.
__global__ void k_rank2(const uint32_t* __restrict__ cand_cnt, const uint32_t* __restrict__ cand_key,
                        const uint32_t* __restrict__ cand_idx, uint32_t* __restrict__ ordered) {
  int b = blockIdx.y;
  uint32_t cnt = cand_cnt[b];
  if (cnt > CCAP) cnt = CCAP;
  uint32_t base = blockIdx.x * RBLK;
  if (base >= cnt) return;  // uniform per block
  __shared__ uint64_t comp[CCAP];   // 32 KB
  __shared__ uint32_t rsum[RBLK];
  int t = threadIdx.x;
  for (uint32_t j = t; j < cnt; j += 256) {
    comp[j] = ((uint64_t)cand_key[b * CCAP + j] << 32) | (uint32_t)(~cand_idx[b * CCAP + j]);
  }
  if (t < RBLK) rsum[t] = 0u;
  __syncthreads();
  uint32_t p = base + (t & 63);     // position: one per lane
  int part = t >> 6;                // wave id = quarter of the scan range
  if (p < cnt) {
    uint64_t mine = comp[p];
    uint32_t lo = (cnt * (uint32_t)part) >> 2;
    uint32_t hi = (cnt * (uint32_t)(part + 1)) >> 2;
    uint32_t r = 0;
    uint32_t j = lo;
    for (; j + 8 <= hi; j += 8) {   // broadcast reads, 8x unrolled
      uint64_t c0 = comp[j], c1 = comp[j + 1], c2 = comp[j + 2], c3 = comp[j + 3];
      uint64_t c4 = comp[j + 4], c5 = comp[j + 5], c6 = comp[j + 6], c7 = comp[j + 7];
      r += (c0 > mine) + (c1 > mine) + (c2 > mine) + (c3 > mine);
      r += (c4 > mine) + (c5 > mine) + (c6 > mine) + (c7 > mine);
    }
    for (; j < hi; ++j) r += (comp[j] > mine) ? 1u : 0u;
    atomicAdd(&rsum[t & 63], r);
  }
  __syncthreads();
  if (part == 0 && p < cnt) {
    uint32_t r = rsum[t & 63];
    if (r < NCROSS) ordered[b * NCROSS + r] = ~(uint32_t)comp[p];
  }
}

// PROVEN GREEN verbatim.
__global__ void k_sort256(const uint32_t* __restrict__ ordered, uint32_t* __restrict__ sel,
                          float* __restrict__ out_si) {
  int b = blockIdx.x;
  int t = threadIdx.x;
  __shared__ uint32_t idxs[TOPK];
  uint32_t v = ordered[b * NCROSS + t];
  idxs[t] = v;
  __syncthreads();
  int r = 0;
  for (int j = 0; j < TOPK; ++j) r += (idxs[j] < v) ? 1 : 0;
  sel[b * TOPK + r] = v;
  out_si[b * TOPK + r] = (float)v;
}

// PROVEN GREEN verbatim.
__global__ void k_gather(const float* __restrict__ features, const float* __restrict__ points,
                         const uint32_t* __restrict__ ordered, const uint32_t* __restrict__ sel,
                         float* __restrict__ out) {
  int g = blockIdx.x;
  int t = threadIdx.x;
  if (g < 1024) {
    int flat = g * 256 + t;
    int row = flat >> 5;
    int c4 = flat & 31;
    int b = row >> 10, j = row & 1023;
    uint32_t idx = ordered[b * NCROSS + j];
    const float4* src = (const float4*)(features + ((size_t)b * NN + idx) * DD);
    ((float4*)(out + OFF_CROSS))[flat] = src[c4];
  } else if (g < 1280) {
    int flat = (g - 1024) * 256 + t;
    int row = flat >> 5;
    int c4 = flat & 31;
    int b = row >> 8, j = row & 255;
    uint32_t idx = sel[b * TOPK + j];
    const float4* src = (const float4*)(features + ((size_t)b * NN + idx) * DD);
    ((float4*)(out + OFF_FEAT))[flat] = src[c4];
  } else {
    int b = g - 1280;
    uint32_t idx = sel[b * TOPK + t];
    const float* src = points + ((size_t)b * NN + idx) * 3;
    float* dst = out + OFF_PTS + ((size_t)b * TOPK + t) * 3;
    dst[0] = src[0];
    dst[1] = src[1];
    dst[2] = src[2];
  }
}

extern "C" void kernel_launch(void* const* d_in, const int* in_sizes, int n_in,
                              void* d_out, int out_size, void* d_ws, size_t ws_size,
                              hipStream_t stream) {
  const float* cen  = (const float*)d_in[0];
  const float* cls  = (const float*)d_in[1];
  const float* pts  = (const float*)d_in[2];
  const float* feat = (const float*)d_in[3];
  float* out = (float*)d_out;

  uint32_t* ws = (uint32_t*)d_ws;
  uint32_t* hist     = ws;                      // BB*NBINS
  uint32_t* cand_cnt = hist + BB * NBINS;       // BB
  uint32_t* cutoff   = cand_cnt + BB;           // BB
  uint32_t* cand_key = cutoff + BB;             // BB*CCAP
  uint32_t* cand_idx = cand_key + BB * CCAP;    // BB*CCAP
  uint32_t* ordered  = cand_idx + BB * CCAP;    // BB*NCROSS
  uint32_t* sel      = ordered + BB * NCROSS;   // BB*TOPK
  uint32_t* keys     = sel + BB * TOPK;         // BB*NN   -> total 3.77 MB (proven)

  int nz = BB * NBINS + BB;  // hist + cand_cnt (adjacent)
  k_init<<<(nz + 255) / 256, 256, 0, stream>>>(hist, nz);
  k_score_v4<<<dim3(196, BB), 256, 0, stream>>>(cen, cls, keys, hist);
  k_select<<<BB, 256, 0, stream>>>(hist, cutoff);
  k_compact<<<dim3((NN + 255) / 256, BB), 256, 0, stream>>>(keys, cutoff, cand_cnt, cand_key, cand_idx);
  k_rank2<<<dim3(CCAP / RBLK, BB), 256, 0, stream>>>(cand_cnt, cand_key, cand_idx, ordered);
  k_sort256<<<BB, 256, 0, stream>>>(ordered, sel, out + OFF_SI);
  k_gather<<<1288, 256, 0, stream>>>(feat, pts, ordered, sel, out);
}

// Round 16
// 142.222 us; speedup vs baseline: 1.1299x; 1.1299x over previous
//
#include <hip/hip_runtime.h>
#include <stdint.h>

#define BB 8
#define NN 100000
#define CC 18
#define DD 128
#define NCROSS 1024
#define TOPK 256
#define NBINS 8192
#define CCAP 4096
#define SEG 3125          // NN / 32
#define RBLK 64           // positions per k_rank2 block

// d_out float offsets (outputs concatenated flat in return order)
#define OFF_PTS 0
#define OFF_FEAT 6144
#define OFF_SI 268288
#define OFF_CROSS 270336

// sigmoid with correctly-rounded f32 exp — bit-matched numpy f32 pipeline
__device__ __forceinline__ float sigf(float x) {
  float e = (float)exp(-(double)x);
  return 1.0f / (1.0f + e);
}

__global__ void k_init(uint32_t* __restrict__ p, int n) {
  int i = blockIdx.x * 256 + threadIdx.x;
  if (i < n) p[i] = 0u;
}

// CHAMPION (r9, 142.4 us): 32 blocks/batch, u32 LDS hist, atomic flush.
// Cold-read-bound: all score variants equal; this one measured lowest.
__global__ void k_score(const float* __restrict__ cen, const float* __restrict__ cls,
                        uint32_t* __restrict__ keys, uint32_t* __restrict__ hist) {
  int b = blockIdx.y;
  int seg = blockIdx.x;
  __shared__ uint32_t h[NBINS];  // 32 KB
  for (int j = threadIdx.x; j < NBINS; j += 256) h[j] = 0u;
  __syncthreads();
  int base = b * NN + seg * SEG;
  for (int it = threadIdx.x; it < SEG; it += 256) {
    int i = base + it;
    const float2* p2 = (const float2*)(cls + (size_t)i * CC);
    float m = -INFINITY;
#pragma unroll
    for (int c = 0; c < CC / 2; ++c) {
      float2 v = p2[c];
      m = fmaxf(m, fmaxf(v.x, v.y));
    }
    // max_c fl(sig_cen*sig_cls_c) == fl(sig_cen * sig(max_c cls_c)) (monotone)
    float s = sigf(m) * sigf(cen[i]);
    uint32_t k = __float_as_uint(s);
    keys[i] = k;
    atomicAdd(&h[k >> 19], 1u);
  }
  __syncthreads();
  for (int j = threadIdx.x; j < NBINS; j += 256) {
    uint32_t v = h[j];
    if (v) atomicAdd(&hist[b * NBINS + j], v);
  }
}

// PROVEN GREEN verbatim.
__global__ void k_select(const uint32_t* __restrict__ hist, uint32_t* __restrict__ cutoff) {
  int b = blockIdx.x;
  int t = threadIdx.x;
  __shared__ uint32_t h[NBINS];     // 32 KB
  __shared__ uint32_t csum[256];
  for (int j = t; j < NBINS; j += 256) h[j] = hist[b * NBINS + j];
  __syncthreads();
  uint32_t s = 0;
  int base = t * 32;
#pragma unroll
  for (int j = 0; j < 32; ++j) s += h[base + ((j + t) & 31)];
  csum[t] = s;
  __syncthreads();
  for (int off = 1; off < 256; off <<= 1) {
    uint32_t v = csum[t];
    uint32_t a = (t + off < 256) ? csum[t + off] : 0u;
    __syncthreads();
    csum[t] = v + a;
    __syncthreads();
  }
  uint32_t St = csum[t];
  uint32_t St1 = (t < 255) ? csum[t + 1] : 0u;
  if (St >= NCROSS && St1 < NCROSS) {
    uint32_t acc = St1;
    int cb = base;
    for (int bin = base + 31; bin >= base; --bin) {
      acc += h[bin];
      if (acc >= NCROSS) { cb = bin; break; }
    }
    cutoff[b] = (uint32_t)cb;
  }
}

// PROVEN GREEN verbatim: wave-aggregated atomics.
__global__ void k_compact(const uint32_t* __restrict__ keys, const uint32_t* __restrict__ cutoff,
                          uint32_t* __restrict__ cand_cnt, uint32_t* __restrict__ cand_key,
                          uint32_t* __restrict__ cand_idx) {
  int b = blockIdx.y;
  int n = blockIdx.x * 256 + threadIdx.x;
  bool pass = false;
  uint32_t k = 0;
  if (n < NN) {
    k = keys[b * NN + n];
    pass = (k >> 19) >= cutoff[b];
  }
  int lane = threadIdx.x & 63;
  unsigned long long mask = __ballot(pass);
  if (mask) {
    int leader = __ffsll(mask) - 1;
    uint32_t wbase = 0;
    if (lane == leader) wbase = atomicAdd(&cand_cnt[b], (uint32_t)__popcll(mask));
    wbase = __shfl(wbase, leader);
    if (pass) {
      uint32_t pos = wbase + (uint32_t)__popcll(mask & ((1ull << lane) - 1ull));
      if (pos < CCAP) {
        cand_key[b * CCAP + pos] = k;
        cand_idx[b * CCAP + pos] = (uint32_t)n;
      }
    }
  }
}

// PROVEN GREEN (r9): 4-wave-per-position broadcast ranking.
__global__ void k_rank2(const uint32_t* __restrict__ cand_cnt, const uint32_t* __restrict__ cand_key,
                        const uint32_t* __restrict__ cand_idx, uint32_t* __restrict__ ordered) {
  int b = blockIdx.y;
  uint32_t cnt = cand_cnt[b];
  if (cnt > CCAP) cnt = CCAP;
  uint32_t base = blockIdx.x * RBLK;
  if (base >= cnt) return;  // uniform per block
  __shared__ uint64_t comp[CCAP];   // 32 KB
  __shared__ uint32_t rsum[RBLK];
  int t = threadIdx.x;
  for (uint32_t j = t; j < cnt; j += 256) {
    comp[j] = ((uint64_t)cand_key[b * CCAP + j] << 32) | (uint32_t)(~cand_idx[b * CCAP + j]);
  }
  if (t < RBLK) rsum[t] = 0u;
  __syncthreads();
  uint32_t p = base + (t & 63);     // position: one per lane
  int part = t >> 6;                // wave id = quarter of the scan range
  if (p < cnt) {
    uint64_t mine = comp[p];
    uint32_t lo = (cnt * (uint32_t)part) >> 2;
    uint32_t hi = (cnt * (uint32_t)(part + 1)) >> 2;
    uint32_t r = 0;
    uint32_t j = lo;
    for (; j + 8 <= hi; j += 8) {   // broadcast reads, 8x unrolled
      uint64_t c0 = comp[j], c1 = comp[j + 1], c2 = comp[j + 2], c3 = comp[j + 3];
      uint64_t c4 = comp[j + 4], c5 = comp[j + 5], c6 = comp[j + 6], c7 = comp[j + 7];
      r += (c0 > mine) + (c1 > mine) + (c2 > mine) + (c3 > mine);
      r += (c4 > mine) + (c5 > mine) + (c6 > mine) + (c7 > mine);
    }
    for (; j < hi; ++j) r += (comp[j] > mine) ? 1u : 0u;
    atomicAdd(&rsum[t & 63], r);
  }
  __syncthreads();
  if (part == 0 && p < cnt) {
    uint32_t r = rsum[t & 63];
    if (r < NCROSS) ordered[b * NCROSS + r] = ~(uint32_t)comp[p];
  }
}

// PROVEN GREEN verbatim.
__global__ void k_sort256(const uint32_t* __restrict__ ordered, uint32_t* __restrict__ sel,
                          float* __restrict__ out_si) {
  int b = blockIdx.x;
  int t = threadIdx.x;
  __shared__ uint32_t idxs[TOPK];
  uint32_t v = ordered[b * NCROSS + t];
  idxs[t] = v;
  __syncthreads();
  int r = 0;
  for (int j = 0; j < TOPK; ++j) r += (idxs[j] < v) ? 1 : 0;
  sel[b * TOPK + r] = v;
  out_si[b * TOPK + r] = (float)v;
}

// PROVEN GREEN verbatim.
__global__ void k_gather(const float* __restrict__ features, const float* __restrict__ points,
                         const uint32_t* __restrict__ ordered, const uint32_t* __restrict__ sel,
                         float* __restrict__ out) {
  int g = blockIdx.x;
  int t = threadIdx.x;
  if (g < 1024) {
    int flat = g * 256 + t;
    int row = flat >> 5;
    int c4 = flat & 31;
    int b = row >> 10, j = row & 1023;
    uint32_t idx = ordered[b * NCROSS + j];
    const float4* src = (const float4*)(features + ((size_t)b * NN + idx) * DD);
    ((float4*)(out + OFF_CROSS))[flat] = src[c4];
  } else if (g < 1280) {
    int flat = (g - 1024) * 256 + t;
    int row = flat >> 5;
    int c4 = flat & 31;
    int b = row >> 8, j = row & 255;
    uint32_t idx = sel[b * TOPK + j];
    const float4* src = (const float4*)(features + ((size_t)b * NN + idx) * DD);
    ((float4*)(out + OFF_FEAT))[flat] = src[c4];
  } else {
    int b = g - 1280;
    uint32_t idx = sel[b * TOPK + t];
    const float* src = points + ((size_t)b * NN + idx) * 3;
    float* dst = out + OFF_PTS + ((size_t)b * TOPK + t) * 3;
    dst[0] = src[0];
    dst[1] = src[1];
    dst[2] = src[2];
  }
}

extern "C" void kernel_launch(void* const* d_in, const int* in_sizes, int n_in,
                              void* d_out, int out_size, void* d_ws, size_t ws_size,
                              hipStream_t stream) {
  const float* cen  = (const float*)d_in[0];
  const float* cls  = (const float*)d_in[1];
  const float* pts  = (const float*)d_in[2];
  const float* feat = (const float*)d_in[3];
  float* out = (float*)d_out;

  uint32_t* ws = (uint32_t*)d_ws;
  uint32_t* hist     = ws;                      // BB*NBINS
  uint32_t* cand_cnt = hist + BB * NBINS;       // BB
  uint32_t* cutoff   = cand_cnt + BB;           // BB
  uint32_t* cand_key = cutoff + BB;             // BB*CCAP
  uint32_t* cand_idx = cand_key + BB * CCAP;    // BB*CCAP
  uint32_t* ordered  = cand_idx + BB * CCAP;    // BB*NCROSS
  uint32_t* sel      = ordered + BB * NCROSS;   // BB*TOPK
  uint32_t* keys     = sel + BB * TOPK;         // BB*NN   -> total 3.77 MB (proven)

  int nz = BB * NBINS + BB;  // hist + cand_cnt (adjacent)
  k_init<<<(nz + 255) / 256, 256, 0, stream>>>(hist, nz);
  k_score<<<dim3(32, BB), 256, 0, stream>>>(cen, cls, keys, hist);
  k_select<<<BB, 256, 0, stream>>>(hist, cutoff);
  k_compact<<<dim3((NN + 255) / 256, BB), 256, 0, stream>>>(keys, cutoff, cand_cnt, cand_key, cand_idx);
  k_rank2<<<dim3(CCAP / RBLK, BB), 256, 0, stream>>>(cand_cnt, cand_key, cand_idx, ordered);
  k_sort256<<<BB, 256, 0, stream>>>(ordered, sel, out + OFF_SI);
  k_gather<<<1288, 256, 0, stream>>>(feat, pts, ordered, sel, out);
}